// Round 1
// baseline (11928.222 us; speedup 1.0000x reference)
//
#include <hip/hip_runtime.h>

#define F_DIM 512
#define H_DIM 2048
#define V_DIM 32000
#define B_DIM 64
#define S_DIM 256
#define ROWS (S_DIM*B_DIM)          // 16384
#define NT_LOG 250                  // 32000/128
#define SCALE 0.04419417382415922f  // 1/sqrt(512)

typedef __attribute__((ext_vector_type(8))) short  short8;
typedef __attribute__((ext_vector_type(4))) float  floatx4;

static __device__ inline unsigned short f2bf(float x){
  unsigned int u = __float_as_uint(x);
  u += 0x7fffu + ((u >> 16) & 1u);           // RNE
  return (unsigned short)(u >> 16);
}
static __device__ inline float bf2f(unsigned short u){
  return __uint_as_float(((unsigned int)u) << 16);
}
static __device__ inline float wsum(float v){
  #pragma unroll
  for(int m = 32; m > 0; m >>= 1) v += __shfl_xor(v, m);
  return v;
}
static __device__ inline void load_lds16(const void* g, void* l){
  __builtin_amdgcn_global_load_lds((const __attribute__((address_space(1))) void*)g,
                                   (__attribute__((address_space(3))) void*)l, 16, 0, 0);
}

// ---------------- casts ----------------
__global__ __launch_bounds__(256) void cast_w(const float* __restrict__ src,
                                              unsigned short* __restrict__ dst, int n){
  int i = blockIdx.x*256 + threadIdx.x;
  int stride = gridDim.x*256;
  for(; i < n; i += stride) dst[i] = f2bf(src[i]);
}
__global__ __launch_bounds__(256) void cast_emb(const float* __restrict__ src,
                                                unsigned short* __restrict__ dst){
  int i = blockIdx.x*256 + threadIdx.x;
  int stride = gridDim.x*256;
  for(; i < V_DIM*F_DIM; i += stride){
    float v = (i < F_DIM) ? 0.f : src[i];    // PAD row (0) zeroed
    dst[i] = f2bf(v);
  }
}

// ---------------- sequential recurrence, one launch per step ----------------
// grid 64: bid -> (jhalf, b-pair {p, p+32}); 256 thr: j = jhalf*256+tid; 2 outputs/thread
__global__ __launch_bounds__(256) void recurrence_step(
    const float* __restrict__ emb, const int* __restrict__ inp,
    const float* __restrict__ see, const float* __restrict__ bias,
    float* __restrict__ cont, int t)
{
  const int jh = blockIdx.x & 1;
  const int p  = blockIdx.x >> 1;          // 0..31
  const int b0 = p, b1 = p + 32;
  const int j  = jh*256 + threadIdx.x;
  const int i0 = inp[b0*S_DIM + t];
  const int i1 = inp[b1*S_DIM + t];
  const float* e0 = emb + (long)i0*F_DIM;
  const float* e1 = emb + (long)i1*F_DIM;
  const float m0 = (i0 != 0) ? 1.f : 0.f;
  const float m1 = (i1 != 0) ? 1.f : 0.f;

  float z0 = bias[j], z1 = bias[j];
  const float* w = see + j;
  #pragma unroll 8
  for(int k = 0; k < F_DIM; k++){
    float wv = w[(long)k*F_DIM];
    z0 += (e0[k]*m0) * wv;
    z1 += (e1[k]*m1) * wv;
  }
  float st0 = 0.f, st1 = 0.f;
  if (t > 0){
    const float* s0 = cont + (long)(t-1)*(B_DIM*F_DIM) + b0*F_DIM;
    const float* s1 = cont + (long)(t-1)*(B_DIM*F_DIM) + b1*F_DIM;
    const float* w2 = see + (long)F_DIM*F_DIM + j;
    #pragma unroll 8
    for(int k = 0; k < F_DIM; k++){
      float wv = w2[(long)k*F_DIM];
      z0 += s0[k] * wv;
      z1 += s1[k] * wv;
    }
    st0 = s0[j]; st1 = s1[j];
  }
  float g0 = 1.f/(1.f + expf(-z0));
  float g1 = 1.f/(1.f + expf(-z1));
  float v0 = e0[j]*m0, v1 = e1[j]*m1;
  cont[(long)t*(B_DIM*F_DIM) + b0*F_DIM + j] = st0*g0 + v0*(1.f - g0);
  cont[(long)t*(B_DIM*F_DIM) + b1*F_DIM + j] = st1*g1 + v1*(1.f - g1);
}

// ---------------- layernorm + bf16 cast; 1 row per wave ----------------
__global__ __launch_bounds__(256) void ln_kernel(const float* __restrict__ cont,
    const float* __restrict__ lg, const float* __restrict__ lb,
    unsigned short* __restrict__ xln)
{
  const int wid = threadIdx.x >> 6, l = threadIdx.x & 63;
  const long row = (long)blockIdx.x*4 + wid;
  const float* x = cont + row*F_DIM;
  float v[8];
  float4 a = *(const float4*)(x + l*8);
  float4 b = *(const float4*)(x + l*8 + 4);
  v[0]=a.x; v[1]=a.y; v[2]=a.z; v[3]=a.w; v[4]=b.x; v[5]=b.y; v[6]=b.z; v[7]=b.w;
  float s = 0.f;
  #pragma unroll
  for(int i=0;i<8;i++) s += v[i];
  s = wsum(s);
  float mu = s * (1.f/512.f);
  float q = 0.f;
  #pragma unroll
  for(int i=0;i<8;i++){ float d = v[i]-mu; q += d*d; }
  q = wsum(q);
  float rs = rsqrtf(q*(1.f/512.f) + 1e-5f);
  short8 o;
  #pragma unroll
  for(int i=0;i<8;i++)
    o[i] = (short)f2bf((v[i]-mu)*rs*lg[l*8+i] + lb[l*8+i]);
  *(short8*)(xln + row*F_DIM + l*8) = o;
}

// ---------------- MFMA GEMM: C[M,N] = A[M,K] * B[N,K]^T (both row-major bf16) ----
// MODE 0: +bias, relu, store bf16.  MODE 1: +bias, store bf16.
// MODE 2: scale by 1/sqrt(F), per-row online-softmax partials (max,sumexp) per 128-col tile.
template<int MODE>
__global__ __launch_bounds__(256) void gemm_bt(
    const unsigned short* __restrict__ A,
    const unsigned short* __restrict__ Bm,
    const float* __restrict__ bias,
    unsigned short* __restrict__ C,
    float2* __restrict__ part,
    int M, int N, int K, int tiles_m, int tiles_n)
{
  __shared__ short As[128*64];
  __shared__ short Bs[128*64];
  __shared__ float sm[2][64][2][2];

  const int bid = blockIdx.x;
  const int mt = bid % tiles_m;
  const int nt = bid / tiles_m;
  const long m0 = (long)mt * 128;
  const long n0 = (long)nt * 128;
  const int tid = threadIdx.x;
  const int l = tid & 63;
  const int wid = tid >> 6;
  const int wr = wid >> 1, wc = wid & 1;
  const int rl = l & 15, rq = l >> 4;

  const short* Ag = (const short*)A + m0 * K;
  const short* Bg = (const short*)Bm + n0 * K;
  const int grow = tid >> 3;   // 0..31
  const int kp = tid & 7;      // 0..7

  floatx4 acc[4][4];
  #pragma unroll
  for(int i=0;i<4;i++)
    #pragma unroll
    for(int j=0;j<4;j++) acc[i][j] = (floatx4)0.f;

  for(int k0 = 0; k0 < K; k0 += 64){
    __syncthreads();
    #pragma unroll
    for(int ro = 0; ro < 128; ro += 32){
      load_lds16(Ag + (long)(ro + grow)*K + k0 + kp*8, (void*)(As + (ro+grow)*64 + kp*8));
      load_lds16(Bg + (long)(ro + grow)*K + k0 + kp*8, (void*)(Bs + (ro+grow)*64 + kp*8));
    }
    __syncthreads();
    #pragma unroll
    for(int kb = 0; kb < 64; kb += 32){
      short8 af[4], bfr[4];
      #pragma unroll
      for(int i=0;i<4;i++) af[i]  = *(const short8*)(As + (wr*64 + i*16 + rl)*64 + kb + rq*8);
      #pragma unroll
      for(int j=0;j<4;j++) bfr[j] = *(const short8*)(Bs + (wc*64 + j*16 + rl)*64 + kb + rq*8);
      #pragma unroll
      for(int i=0;i<4;i++)
        #pragma unroll
        for(int j=0;j<4;j++)
          acc[i][j] = __builtin_amdgcn_mfma_f32_16x16x32_bf16(af[i], bfr[j], acc[i][j], 0, 0, 0);
    }
  }

  const long mb = m0 + wr*64;
  const long nb = n0 + wc*64;
  if (MODE == 0 || MODE == 1){
    #pragma unroll
    for(int j=0;j<4;j++){
      float bj = bias[nb + j*16 + rl];
      #pragma unroll
      for(int i=0;i<4;i++){
        #pragma unroll
        for(int r=0;r<4;r++){
          float v = acc[i][j][r] + bj;
          if (MODE == 0) v = fmaxf(v, 0.f);
          C[(mb + i*16 + rq*4 + r)*N + nb + j*16 + rl] = f2bf(v);
        }
      }
    }
  } else {
    // rows of this wave: i*16 + rq*4 + r; cols: 16-lane groups over j-tiles
    #pragma unroll
    for(int i=0;i<4;i++){
      #pragma unroll
      for(int r=0;r<4;r++){
        float mx = -3.4e38f;
        #pragma unroll
        for(int j=0;j<4;j++) mx = fmaxf(mx, acc[i][j][r]);
        #pragma unroll
        for(int d=1; d<16; d<<=1) mx = fmaxf(mx, __shfl_xor(mx, d));
        float ms = mx * SCALE;
        float sv = 0.f;
        #pragma unroll
        for(int j=0;j<4;j++) sv += expf(acc[i][j][r]*SCALE - ms);
        #pragma unroll
        for(int d=1; d<16; d<<=1) sv += __shfl_xor(sv, d);
        if (rl == 0){
          int rowl = i*16 + rq*4 + r;
          sm[wr][rowl][wc][0] = ms;
          sm[wr][rowl][wc][1] = sv;
        }
      }
    }
    __syncthreads();
    if (tid < 128){
      int wr2 = tid >> 6, rowl = tid & 63;
      float ma = sm[wr2][rowl][0][0], sa = sm[wr2][rowl][0][1];
      float mb2= sm[wr2][rowl][1][0], sb = sm[wr2][rowl][1][1];
      float Mn = fmaxf(ma, mb2);
      float Ln = sa*expf(ma - Mn) + sb*expf(mb2 - Mn);
      float2 o; o.x = Mn; o.y = Ln;
      part[(m0 + wr2*64 + rowl)*tiles_n + nt] = o;
    }
  }
}

// ---------------- target logit: dot(OUT[row], EMB[tgt]) * scale; 1 row/wave ---
__global__ __launch_bounds__(256) void tlogit_kernel(const unsigned short* __restrict__ outb,
    const unsigned short* __restrict__ embb, const int* __restrict__ tgt,
    float* __restrict__ TL)
{
  long gw = (long)blockIdx.x*4 + (threadIdx.x >> 6);
  int l = threadIdx.x & 63;
  int t = (int)(gw >> 6), b = (int)(gw & 63);
  int tg = tgt[b*S_DIM + t];
  const unsigned short* o = outb + gw*F_DIM;
  const unsigned short* e = embb + (long)tg*F_DIM;
  short8 ov = *(const short8*)(o + l*8);
  short8 ev = *(const short8*)(e + l*8);
  float s = 0.f;
  #pragma unroll
  for(int i=0;i<8;i++) s += bf2f((unsigned short)ov[i]) * bf2f((unsigned short)ev[i]);
  s = wsum(s);
  if (l == 0) TL[gw] = s * SCALE;
}

// ---------------- merge 250 partials per row -> nll; 1 row/wave ----------------
__global__ __launch_bounds__(256) void lse_kernel(const float2* __restrict__ part,
    const float* __restrict__ TL, float* __restrict__ nll)
{
  long row = (long)blockIdx.x*4 + (threadIdx.x >> 6);
  int l = threadIdx.x & 63;
  float M = -3.4e38f, L = 0.f;
  for(int c = l; c < NT_LOG; c += 64){
    float2 pv = part[row*NT_LOG + c];
    float Mn = fmaxf(M, pv.x);
    L = L*expf(M - Mn) + pv.y*expf(pv.x - Mn);
    M = Mn;
  }
  #pragma unroll
  for(int d=1; d<64; d<<=1){
    float Mo = __shfl_xor(M, d), Lo = __shfl_xor(L, d);
    float Mn = fmaxf(M, Mo);
    L = L*expf(M - Mn) + Lo*expf(Mo - Mn);
    M = Mn;
  }
  if (l == 0) nll[row] = (M + logf(L)) - TL[row];
}

// ---------------- masked per-step mean, then mean over steps ----------------
__global__ __launch_bounds__(256) void loss_kernel(const float* __restrict__ nll,
    const int* __restrict__ tgt, float* __restrict__ out)
{
  int t = threadIdx.x;   // 256 steps, 1/thread
  float s = 0.f; int cnt = 0;
  for(int b = 0; b < B_DIM; b++){
    int v = tgt[b*S_DIM + t];
    if (v != 0){ s += nll[(long)t*B_DIM + b]; cnt++; }
  }
  float li = s / fmaxf((float)cnt, 1.f);
  li = wsum(li);
  __shared__ float red[4];
  if ((t & 63) == 0) red[t >> 6] = li;
  __syncthreads();
  if (t == 0) out[0] = (red[0]+red[1]+red[2]+red[3]) * (1.f/256.f);
}

extern "C" void kernel_launch(void* const* d_in, const int* in_sizes, int n_in,
                              void* d_out, int out_size, void* d_ws, size_t ws_size,
                              hipStream_t stream)
{
  const int*   inp   = (const int*)d_in[0];
  const int*   tgt   = (const int*)d_in[1];
  const float* see   = (const float*)d_in[2];
  const float* bias  = (const float*)d_in[3];
  const float* W_in  = (const float*)d_in[4];
  const float* b_in  = (const float*)d_in[5];
  const float* W_out = (const float*)d_in[6];
  const float* b_out = (const float*)d_in[7];
  const float* ln_g  = (const float*)d_in[8];
  const float* ln_b  = (const float*)d_in[9];
  const float* emb   = (const float*)d_in[10];

  char* p = (char*)d_ws;
  float* CONT          = (float*)p;          p += (size_t)ROWS*F_DIM*4;   // 33.55 MB
  unsigned short* XLN  = (unsigned short*)p; p += (size_t)ROWS*F_DIM*2;   // 16.78 MB
  unsigned short* Hb   = (unsigned short*)p; p += (size_t)ROWS*H_DIM*2;   // 67.11 MB
  unsigned short* OUTb = (unsigned short*)p; p += (size_t)ROWS*F_DIM*2;   // 16.78 MB
  unsigned short* EMBb = (unsigned short*)p; p += (size_t)V_DIM*F_DIM*2;  // 32.77 MB
  unsigned short* WINb = (unsigned short*)p; p += (size_t)H_DIM*F_DIM*2;  //  2.10 MB
  unsigned short* WOUTb= (unsigned short*)p; p += (size_t)F_DIM*H_DIM*2;  //  2.10 MB
  float2* PART         = (float2*)p;         p += (size_t)ROWS*NT_LOG*8;  // 32.77 MB
  float* TL            = (float*)p;          p += (size_t)ROWS*4;
  float* NLL           = (float*)p;          p += (size_t)ROWS*4;

  cast_emb<<<4096, 256, 0, stream>>>(emb, EMBb);
  cast_w<<<2048, 256, 0, stream>>>(W_in,  WINb,  H_DIM*F_DIM);
  cast_w<<<2048, 256, 0, stream>>>(W_out, WOUTb, F_DIM*H_DIM);

  for(int t = 0; t < S_DIM; t++)
    recurrence_step<<<64, 256, 0, stream>>>(emb, inp, see, bias, CONT, t);

  ln_kernel<<<ROWS/4, 256, 0, stream>>>(CONT, ln_g, ln_b, XLN);
  gemm_bt<0><<<128*16,  256, 0, stream>>>(XLN,  WINb,  b_in,  Hb,   nullptr, ROWS, H_DIM, F_DIM, 128, 16);
  gemm_bt<1><<<128*4,   256, 0, stream>>>(Hb,   WOUTb, b_out, OUTb, nullptr, ROWS, F_DIM, H_DIM, 128, 4);
  tlogit_kernel<<<ROWS/4, 256, 0, stream>>>(OUTb, EMBb, tgt, TL);
  gemm_bt<2><<<128*NT_LOG, 256, 0, stream>>>(OUTb, EMBb, nullptr, nullptr, PART, ROWS, V_DIM, F_DIM, 128, NT_LOG);
  lse_kernel<<<ROWS/4, 256, 0, stream>>>(PART, TL, NLL);
  loss_kernel<<<1, 256, 0, stream>>>(NLL, tgt, (float*)d_out);
}

// Round 2
// 3747.607 us; speedup vs baseline: 3.1829x; 3.1829x over previous
//
#include <hip/hip_runtime.h>

#define F_DIM 512
#define H_DIM 2048
#define V_DIM 32000
#define B_DIM 64
#define S_DIM 256
#define ROWS (S_DIM*B_DIM)          // 16384
#define NT_LOG 250                  // 32000/128
#define SCALE 0.04419417382415922f  // 1/sqrt(512)
#define RB_BLOCKS 16

typedef __attribute__((ext_vector_type(8))) short  short8;
typedef __attribute__((ext_vector_type(4))) float  floatx4;

static __device__ inline unsigned short f2bf(float x){
  unsigned int u = __float_as_uint(x);
  u += 0x7fffu + ((u >> 16) & 1u);           // RNE
  return (unsigned short)(u >> 16);
}
static __device__ inline float bf2f(unsigned short u){
  return __uint_as_float(((unsigned int)u) << 16);
}
static __device__ inline float wsum(float v){
  #pragma unroll
  for(int m = 32; m > 0; m >>= 1) v += __shfl_xor(v, m);
  return v;
}
static __device__ inline void load_lds16(const void* g, void* l){
  __builtin_amdgcn_global_load_lds((const __attribute__((address_space(1))) void*)g,
                                   (__attribute__((address_space(3))) void*)l, 16, 0, 0);
}

// ---------------- casts ----------------
__global__ __launch_bounds__(256) void cast_w(const float* __restrict__ src,
                                              unsigned short* __restrict__ dst, int n){
  int i = blockIdx.x*256 + threadIdx.x;
  int stride = gridDim.x*256;
  for(; i < n; i += stride) dst[i] = f2bf(src[i]);
}
__global__ __launch_bounds__(256) void cast_emb(const float* __restrict__ src,
                                                unsigned short* __restrict__ dst){
  int i = blockIdx.x*256 + threadIdx.x;
  int stride = gridDim.x*256;
  for(; i < V_DIM*F_DIM; i += stride){
    float v = (i < F_DIM) ? 0.f : src[i];    // PAD row (0) zeroed
    dst[i] = f2bf(v);
  }
}

// ---------------- prep: see^T halves in bf16 ----------------
// TT[n*512+k] = see[k*512+n]; BT[n*512+k] = see[(512+k)*512+n]
__global__ __launch_bounds__(256) void prep_see(const float* __restrict__ see,
    unsigned short* __restrict__ TT, unsigned short* __restrict__ BT){
  int n = blockIdx.x;
  for(int k = threadIdx.x; k < 512; k += 256){
    TT[n*512 + k] = f2bf(see[(long)k*512 + n]);
    BT[n*512 + k] = f2bf(see[(long)(512+k)*512 + n]);
  }
}

// ---------------- gather embedding rows per (t,b), bf16; row = t*64+b -------
__global__ __launch_bounds__(256) void gather_vecs(const float* __restrict__ emb,
    const int* __restrict__ inp, unsigned short* __restrict__ V){
  long row = (long)blockIdx.x*4 + (threadIdx.x >> 6);
  int l = threadIdx.x & 63;
  int t = (int)(row >> 6), b = (int)(row & 63);
  int idx = inp[b*S_DIM + t];
  short8 o;
  if (idx == 0){
    #pragma unroll
    for(int i=0;i<8;i++) o[i] = 0;
  } else {
    const float* e = emb + (long)idx*F_DIM + l*8;
    float4 a = *(const float4*)e;
    float4 bq = *(const float4*)(e + 4);
    o[0]=(short)f2bf(a.x); o[1]=(short)f2bf(a.y); o[2]=(short)f2bf(a.z); o[3]=(short)f2bf(a.w);
    o[4]=(short)f2bf(bq.x);o[5]=(short)f2bf(bq.y);o[6]=(short)f2bf(bq.z);o[7]=(short)f2bf(bq.w);
  }
  *(short8*)(V + row*F_DIM + l*8) = o;
}

// ---------------- persistent recurrence ----------------
// 16 blocks x 256 thr. Block owns cols [bid*32, bid*32+32). Wave w = m-tile (rows w*16..).
// see_bot^T frags in VGPRs; state ping-pong bf16 in global (L2-resident).
__global__ __launch_bounds__(256, 1) void recurrence_persistent(
    const unsigned short* __restrict__ VECS,   // [16384,512] bf16
    const float* __restrict__ Z,               // [16384,512] fp32 = vecs@seeTop + bias
    const unsigned short* __restrict__ WBT,    // seeBotT [n=512][k=512] bf16
    float* __restrict__ cont,                  // [256*64,512] fp32
    unsigned short* __restrict__ SP,           // [2][64*512] bf16 ping-pong
    unsigned int* __restrict__ bar)
{
  const int tid = threadIdx.x;
  const int w  = tid >> 6;
  const int l  = tid & 63;
  const int rl = l & 15, rq = l >> 4;
  const int nb = blockIdx.x * 32;

  // B fragments: 2 n-tiles x 16 k-steps, persistent in VGPRs
  short8 Bf[2][16];
  #pragma unroll
  for(int nt=0; nt<2; nt++)
    #pragma unroll
    for(int ks=0; ks<16; ks++)
      Bf[nt][ks] = *(const short8*)((const short*)WBT + (long)(nb + nt*16 + rl)*512 + ks*32 + rq*8);

  float s_old[2][4];
  #pragma unroll
  for(int nt=0;nt<2;nt++)
    #pragma unroll
    for(int r=0;r<4;r++) s_old[nt][r] = 0.f;

  for(int t = 0; t < S_DIM; t++){
    floatx4 acc0 = (floatx4)0.f, acc1 = (floatx4)0.f;
    if (t > 0){
      const short* sb = (const short*)SP + ((t-1)&1)*(64*512);
      short8 Af[16];
      #pragma unroll
      for(int ks=0; ks<16; ks++)
        Af[ks] = *(const short8*)(sb + (long)(w*16 + rl)*512 + ks*32 + rq*8);
      #pragma unroll
      for(int ks=0; ks<16; ks++){
        acc0 = __builtin_amdgcn_mfma_f32_16x16x32_bf16(Af[ks], Bf[0][ks], acc0, 0, 0, 0);
        acc1 = __builtin_amdgcn_mfma_f32_16x16x32_bf16(Af[ks], Bf[1][ks], acc1, 0, 0, 0);
      }
    }
    const long rowbase = (long)t*64;
    unsigned short* spw = (unsigned short*)SP + (t&1)*(64*512);
    #pragma unroll
    for(int nt=0; nt<2; nt++){
      #pragma unroll
      for(int r=0; r<4; r++){
        int b = w*16 + rq*4 + r;
        long row = rowbase + b;
        int col = nb + nt*16 + rl;
        float zb = (nt==0) ? acc0[r] : acc1[r];
        float z = Z[row*512 + col] + zb;
        float g = 1.f/(1.f + __expf(-z));
        float v = bf2f(VECS[row*512 + col]);
        float s = s_old[nt][r]*g + v*(1.f - g);
        s_old[nt][r] = s;
        cont[row*512 + col] = s;
        spw[b*512 + col] = f2bf(s);
      }
    }
    // grid barrier (monotone counter, device scope)
    __threadfence();
    __syncthreads();
    if (tid == 0){
      __hip_atomic_fetch_add(bar, 1u, __ATOMIC_RELEASE, __HIP_MEMORY_SCOPE_AGENT);
      unsigned tgt = RB_BLOCKS*(unsigned)(t+1);
      while (__hip_atomic_load(bar, __ATOMIC_ACQUIRE, __HIP_MEMORY_SCOPE_AGENT) < tgt)
        __builtin_amdgcn_s_sleep(2);
    }
    __syncthreads();
    __threadfence();
  }
}

// ---------------- layernorm + bf16 cast; 1 row per wave ----------------
__global__ __launch_bounds__(256) void ln_kernel(const float* __restrict__ cont,
    const float* __restrict__ lg, const float* __restrict__ lb,
    unsigned short* __restrict__ xln)
{
  const int wid = threadIdx.x >> 6, l = threadIdx.x & 63;
  const long row = (long)blockIdx.x*4 + wid;
  const float* x = cont + row*F_DIM;
  float v[8];
  float4 a = *(const float4*)(x + l*8);
  float4 b = *(const float4*)(x + l*8 + 4);
  v[0]=a.x; v[1]=a.y; v[2]=a.z; v[3]=a.w; v[4]=b.x; v[5]=b.y; v[6]=b.z; v[7]=b.w;
  float s = 0.f;
  #pragma unroll
  for(int i=0;i<8;i++) s += v[i];
  s = wsum(s);
  float mu = s * (1.f/512.f);
  float q = 0.f;
  #pragma unroll
  for(int i=0;i<8;i++){ float d = v[i]-mu; q += d*d; }
  q = wsum(q);
  float rs = rsqrtf(q*(1.f/512.f) + 1e-5f);
  short8 o;
  #pragma unroll
  for(int i=0;i<8;i++)
    o[i] = (short)f2bf((v[i]-mu)*rs*lg[l*8+i] + lb[l*8+i]);
  *(short8*)(xln + row*F_DIM + l*8) = o;
}

// ---------------- MFMA GEMM: C[M,N] = A[M,K] * B[N,K]^T (both row-major bf16) ----
// MODE 0: +bias, relu, store bf16.  MODE 1: +bias, store bf16.
// MODE 2: scale by 1/sqrt(F), per-row online-softmax partials per 128-col tile.
// MODE 3: +bias, store fp32 (Cf).
template<int MODE>
__global__ __launch_bounds__(256) void gemm_bt(
    const unsigned short* __restrict__ A,
    const unsigned short* __restrict__ Bm,
    const float* __restrict__ bias,
    unsigned short* __restrict__ C,
    float2* __restrict__ part,
    float* __restrict__ Cf,
    int M, int N, int K, int tiles_m, int tiles_n)
{
  __shared__ short As[128*64];
  __shared__ short Bs[128*64];
  __shared__ float sm[2][64][2][2];

  const int bid = blockIdx.x;
  const int mt = bid % tiles_m;
  const int nt = bid / tiles_m;
  const long m0 = (long)mt * 128;
  const long n0 = (long)nt * 128;
  const int tid = threadIdx.x;
  const int l = tid & 63;
  const int wid = tid >> 6;
  const int wr = wid >> 1, wc = wid & 1;
  const int rl = l & 15, rq = l >> 4;

  const short* Ag = (const short*)A + m0 * K;
  const short* Bg = (const short*)Bm + n0 * K;
  const int grow = tid >> 3;   // 0..31
  const int kp = tid & 7;      // 0..7

  floatx4 acc[4][4];
  #pragma unroll
  for(int i=0;i<4;i++)
    #pragma unroll
    for(int j=0;j<4;j++) acc[i][j] = (floatx4)0.f;

  for(int k0 = 0; k0 < K; k0 += 64){
    __syncthreads();
    #pragma unroll
    for(int ro = 0; ro < 128; ro += 32){
      load_lds16(Ag + (long)(ro + grow)*K + k0 + kp*8, (void*)(As + (ro+grow)*64 + kp*8));
      load_lds16(Bg + (long)(ro + grow)*K + k0 + kp*8, (void*)(Bs + (ro+grow)*64 + kp*8));
    }
    __syncthreads();
    #pragma unroll
    for(int kb = 0; kb < 64; kb += 32){
      short8 af[4], bfr[4];
      #pragma unroll
      for(int i=0;i<4;i++) af[i]  = *(const short8*)(As + (wr*64 + i*16 + rl)*64 + kb + rq*8);
      #pragma unroll
      for(int j=0;j<4;j++) bfr[j] = *(const short8*)(Bs + (wc*64 + j*16 + rl)*64 + kb + rq*8);
      #pragma unroll
      for(int i=0;i<4;i++)
        #pragma unroll
        for(int j=0;j<4;j++)
          acc[i][j] = __builtin_amdgcn_mfma_f32_16x16x32_bf16(af[i], bfr[j], acc[i][j], 0, 0, 0);
    }
  }

  const long mb = m0 + wr*64;
  const long nb = n0 + wc*64;
  if (MODE == 0 || MODE == 1 || MODE == 3){
    #pragma unroll
    for(int j=0;j<4;j++){
      float bj = bias[nb + j*16 + rl];
      #pragma unroll
      for(int i=0;i<4;i++){
        #pragma unroll
        for(int r=0;r<4;r++){
          float v = acc[i][j][r] + bj;
          if (MODE == 0) v = fmaxf(v, 0.f);
          if (MODE == 3)
            Cf[(mb + i*16 + rq*4 + r)*N + nb + j*16 + rl] = v;
          else
            C[(mb + i*16 + rq*4 + r)*N + nb + j*16 + rl] = f2bf(v);
        }
      }
    }
  } else {
    #pragma unroll
    for(int i=0;i<4;i++){
      #pragma unroll
      for(int r=0;r<4;r++){
        float mx = -3.4e38f;
        #pragma unroll
        for(int j=0;j<4;j++) mx = fmaxf(mx, acc[i][j][r]);
        #pragma unroll
        for(int d=1; d<16; d<<=1) mx = fmaxf(mx, __shfl_xor(mx, d));
        float ms = mx * SCALE;
        float sv = 0.f;
        #pragma unroll
        for(int j=0;j<4;j++) sv += expf(acc[i][j][r]*SCALE - ms);
        #pragma unroll
        for(int d=1; d<16; d<<=1) sv += __shfl_xor(sv, d);
        if (rl == 0){
          int rowl = i*16 + rq*4 + r;
          sm[wr][rowl][wc][0] = ms;
          sm[wr][rowl][wc][1] = sv;
        }
      }
    }
    __syncthreads();
    if (tid < 128){
      int wr2 = tid >> 6, rowl = tid & 63;
      float ma = sm[wr2][rowl][0][0], sa = sm[wr2][rowl][0][1];
      float mb2= sm[wr2][rowl][1][0], sb = sm[wr2][rowl][1][1];
      float Mn = fmaxf(ma, mb2);
      float Ln = sa*expf(ma - Mn) + sb*expf(mb2 - Mn);
      float2 o; o.x = Mn; o.y = Ln;
      part[(m0 + wr2*64 + rowl)*tiles_n + nt] = o;
    }
  }
}

// ---------------- target logit ----------------
__global__ __launch_bounds__(256) void tlogit_kernel(const unsigned short* __restrict__ outb,
    const unsigned short* __restrict__ embb, const int* __restrict__ tgt,
    float* __restrict__ TL)
{
  long gw = (long)blockIdx.x*4 + (threadIdx.x >> 6);
  int l = threadIdx.x & 63;
  int t = (int)(gw >> 6), b = (int)(gw & 63);
  int tg = tgt[b*S_DIM + t];
  const unsigned short* o = outb + gw*F_DIM;
  const unsigned short* e = embb + (long)tg*F_DIM;
  short8 ov = *(const short8*)(o + l*8);
  short8 ev = *(const short8*)(e + l*8);
  float s = 0.f;
  #pragma unroll
  for(int i=0;i<8;i++) s += bf2f((unsigned short)ov[i]) * bf2f((unsigned short)ev[i]);
  s = wsum(s);
  if (l == 0) TL[gw] = s * SCALE;
}

// ---------------- merge partials -> nll ----------------
__global__ __launch_bounds__(256) void lse_kernel(const float2* __restrict__ part,
    const float* __restrict__ TL, float* __restrict__ nll)
{
  long row = (long)blockIdx.x*4 + (threadIdx.x >> 6);
  int l = threadIdx.x & 63;
  float M = -3.4e38f, L = 0.f;
  for(int c = l; c < NT_LOG; c += 64){
    float2 pv = part[row*NT_LOG + c];
    float Mn = fmaxf(M, pv.x);
    L = L*expf(M - Mn) + pv.y*expf(pv.x - Mn);
    M = Mn;
  }
  #pragma unroll
  for(int d=1; d<64; d<<=1){
    float Mo = __shfl_xor(M, d), Lo = __shfl_xor(L, d);
    float Mn = fmaxf(M, Mo);
    L = L*expf(M - Mn) + Lo*expf(Mo - Mn);
    M = Mn;
  }
  if (l == 0) nll[row] = (M + logf(L)) - TL[row];
}

// ---------------- final loss ----------------
__global__ __launch_bounds__(256) void loss_kernel(const float* __restrict__ nll,
    const int* __restrict__ tgt, float* __restrict__ out)
{
  int t = threadIdx.x;
  float s = 0.f; int cnt = 0;
  for(int b = 0; b < B_DIM; b++){
    int v = tgt[b*S_DIM + t];
    if (v != 0){ s += nll[(long)t*B_DIM + b]; cnt++; }
  }
  float li = s / fmaxf((float)cnt, 1.f);
  li = wsum(li);
  __shared__ float red[4];
  if ((t & 63) == 0) red[t >> 6] = li;
  __syncthreads();
  if (t == 0) out[0] = (red[0]+red[1]+red[2]+red[3]) * (1.f/256.f);
}

extern "C" void kernel_launch(void* const* d_in, const int* in_sizes, int n_in,
                              void* d_out, int out_size, void* d_ws, size_t ws_size,
                              hipStream_t stream)
{
  const int*   inp   = (const int*)d_in[0];
  const int*   tgt   = (const int*)d_in[1];
  const float* see   = (const float*)d_in[2];
  const float* bias  = (const float*)d_in[3];
  const float* W_in  = (const float*)d_in[4];
  const float* b_in  = (const float*)d_in[5];
  const float* W_out = (const float*)d_in[6];
  const float* b_out = (const float*)d_in[7];
  const float* ln_g  = (const float*)d_in[8];
  const float* ln_b  = (const float*)d_in[9];
  const float* emb   = (const float*)d_in[10];

  char* p = (char*)d_ws;
  float* CONT          = (float*)p;          p += (size_t)ROWS*F_DIM*4;   // 33.6 MB
  unsigned short* XLN  = (unsigned short*)p; p += (size_t)ROWS*F_DIM*2;   // 16.8 MB
  unsigned short* Hb   = (unsigned short*)p; p += (size_t)ROWS*H_DIM*2;   // 67.1 MB
  unsigned short* OUTb = (unsigned short*)p; p += (size_t)ROWS*F_DIM*2;   // 16.8 MB
  unsigned short* EMBb = (unsigned short*)p; p += (size_t)V_DIM*F_DIM*2;  // 32.8 MB
  unsigned short* WINb = (unsigned short*)p; p += (size_t)H_DIM*F_DIM*2;  //  2.1 MB
  unsigned short* WOUTb= (unsigned short*)p; p += (size_t)F_DIM*H_DIM*2;  //  2.1 MB
  float2* PART         = (float2*)p;         p += (size_t)ROWS*NT_LOG*8;  // 32.8 MB
  float* TL            = (float*)p;          p += (size_t)ROWS*4;
  float* NLL           = (float*)p;          p += (size_t)ROWS*4;
  unsigned short* VECSb= (unsigned short*)p; p += (size_t)ROWS*F_DIM*2;   // 16.8 MB
  float* Zf            = (float*)p;          p += (size_t)ROWS*F_DIM*4;   // 33.6 MB
  unsigned short* SEETT= (unsigned short*)p; p += (size_t)F_DIM*F_DIM*2;  //  0.5 MB
  unsigned short* SEEBT= (unsigned short*)p; p += (size_t)F_DIM*F_DIM*2;  //  0.5 MB
  unsigned short* SP   = (unsigned short*)p; p += (size_t)2*B_DIM*F_DIM*2;//  0.26 MB
  unsigned int* BAR    = (unsigned int*)p;   p += 256;

  // independent prep
  cast_emb<<<4096, 256, 0, stream>>>(emb, EMBb);
  cast_w<<<2048, 256, 0, stream>>>(W_in,  WINb,  H_DIM*F_DIM);
  cast_w<<<2048, 256, 0, stream>>>(W_out, WOUTb, F_DIM*H_DIM);
  prep_see<<<512, 256, 0, stream>>>(see, SEETT, SEEBT);
  gather_vecs<<<ROWS/4, 256, 0, stream>>>(emb, inp, VECSb);

  // Z = vecs @ see_top + bias  (fp32 out)
  gemm_bt<3><<<128*4, 256, 0, stream>>>(VECSb, SEETT, bias, nullptr, nullptr, Zf,
                                        ROWS, F_DIM, F_DIM, 128, 4);

  // persistent recurrence
  hipMemsetAsync(BAR, 0, 256, stream);
  recurrence_persistent<<<RB_BLOCKS, 256, 0, stream>>>(VECSb, Zf, SEEBT, CONT, SP, BAR);

  // downstream
  ln_kernel<<<ROWS/4, 256, 0, stream>>>(CONT, ln_g, ln_b, XLN);
  gemm_bt<0><<<128*16, 256, 0, stream>>>(XLN,  WINb,  b_in,  Hb,   nullptr, nullptr, ROWS, H_DIM, F_DIM, 128, 16);
  gemm_bt<1><<<128*4,  256, 0, stream>>>(Hb,   WOUTb, b_out, OUTb, nullptr, nullptr, ROWS, F_DIM, H_DIM, 128, 4);
  tlogit_kernel<<<ROWS/4, 256, 0, stream>>>(OUTb, EMBb, tgt, TL);
  gemm_bt<2><<<128*NT_LOG, 256, 0, stream>>>(OUTb, EMBb, nullptr, nullptr, PART, nullptr, ROWS, V_DIM, F_DIM, 128, NT_LOG);
  lse_kernel<<<ROWS/4, 256, 0, stream>>>(PART, TL, NLL);
  loss_kernel<<<1, 256, 0, stream>>>(NLL, tgt, (float*)d_out);
}